// Round 12
// baseline (359.562 us; speedup 1.0000x reference)
//
#include <hip/hip_runtime.h>
#include <hip/hip_cooperative_groups.h>

namespace cg = cooperative_groups;

#define B_ 8
#define L_ 2048
#define D_ 512
#define BI 128            // i-rows per block
#define BJ 64
#define NJB (L_ / BJ)     // 32

typedef __attribute__((ext_vector_type(4))) float  floatx4;
typedef __attribute__((ext_vector_type(8))) _Float16 halfx8;
typedef __attribute__((ext_vector_type(4))) int    intx4;

#define KSCALE 0.51012599f  // log2(e)/sqrt(8): exp2-domain softmax

static __device__ __forceinline__ unsigned short f2h_bits(float x) {
  _Float16 h = (_Float16)x;
  return __builtin_bit_cast(unsigned short, h);
}
static __device__ __forceinline__ int pack2(float a, float b) {
  return (int)((unsigned int)f2h_bits(a) | ((unsigned int)f2h_bits(b) << 16));
}

typedef __attribute__((address_space(1))) const unsigned short gus;
typedef __attribute__((address_space(3))) unsigned short lus;
static __device__ __forceinline__ void gld_lds16(const unsigned short* g,
                                                 unsigned short* l) {
  __builtin_amdgcn_global_load_lds((gus*)g, (lus*)l, 16, 0, 0);
}

// ===========================================================================
// FUSED cooperative kernel — prep phase + grid.sync() + flash phase.
//  Launched via hipLaunchCooperativeKernel (harness-supported; occupancy is
//  VALIDATED at launch — round-11 lesson: a hand-rolled ticket/spin sync
//  hangs under rocprof serialized replay; grid.sync() is the sanctioned way).
//  grid 256 x 512 thr, __launch_bounds__(512,2); LDS 150 KB -> 1 block/CU,
//  256 blocks = 256 CUs -> cooperative co-residency requirement satisfied.
//  PREP: block (b=bid&7, t2=bid>>3) preps j-tile t2 of batch b (64 rows x D):
//    Kh linear f16 (16B stores); Qh = in*qw*KSCALE (if ws fits); Vfrag in
//    MFMA-B fragment order (mapping identical to rounds 4-10, proven).
//    vtile scratch aliased onto the Ksh region (flash DMA overwrites later).
//  FLASH: VERBATIM round-9 v6 (verified 170 us). Round-10 lesson: L2-direct
//    K fragments are latency-exposed at 2 waves/SIMD — K stays LDS-staged.
//    Round-6: 32 rows/wave spills at the 256-VGPR arch cap. Round-7: setprio
//    + prefetch-hoist regress (lockstep). Rounds 7/8: schedule variants flat.
//  RULE-20: all qf/s/O/vf loops fully unrolled.
// ===========================================================================
__global__ __launch_bounds__(512, 2) void fused(const float* __restrict__ in,
                                                const float* __restrict__ qw,
                                                const float* __restrict__ kw,
                                                const float* __restrict__ vw,
                                                unsigned short* __restrict__ Kh,
                                                unsigned short* __restrict__ Vfrag,
                                                unsigned short* __restrict__ Qh,
                                                float* __restrict__ out,
                                                int has_qh) {
  const int bid  = blockIdx.x;
  const int b    = bid & 7;            // batch == XCD (round-robin dispatch)
  const int t2   = bid >> 3;           // 0..31
  const int tid  = threadIdx.x;
  const int w    = tid >> 6;
  const int lane = tid & 63;
  const int ln16 = lane & 15;
  const int quad = lane >> 4;

  __shared__ unsigned short Ksh[2][BJ][D_];  // 128 KB dbuf (prep vtile alias)
  __shared__ unsigned short Psh[BI][72];     // 18.4 KB
  __shared__ float Alsh[BI];                 // per-jb rescale alpha
  __shared__ float Lsh[BI];                  // final l

  // ================= PREP phase: j-tile t2 of batch b =================
  {
    const int lt = t2 * 64;            // row base (l index)
    const int r  = tid >> 3;           // 0..63
    const int c8 = (tid & 7) * 8;      // 0..56
    unsigned short* vt0 = &Ksh[0][0][0];        // [64][66] scratch x2
    unsigned short* vt1 = vt0 + 64 * 66;
    for (int dt2 = 0; dt2 < 8; ++dt2) {
      unsigned short* vt = (dt2 & 1) ? vt1 : vt0;
      const int dt = dt2 * 64;
      size_t wi_ = (size_t)(lt + r) * D_ + (dt + c8);
      size_t gi  = ((size_t)b * L_ + (lt + r)) * D_ + (dt + c8);
      float4 a0 = *(const float4*)(in + gi);
      float4 a1 = *(const float4*)(in + gi + 4);
      float4 k0 = *(const float4*)(kw + wi_);
      float4 k1 = *(const float4*)(kw + wi_ + 4);
      float4 v0 = *(const float4*)(vw + wi_);
      float4 v1 = *(const float4*)(vw + wi_ + 4);
      intx4 kp;
      kp[0] = pack2(a0.x * k0.x, a0.y * k0.y);
      kp[1] = pack2(a0.z * k0.z, a0.w * k0.w);
      kp[2] = pack2(a1.x * k1.x, a1.y * k1.y);
      kp[3] = pack2(a1.z * k1.z, a1.w * k1.w);
      *(intx4*)(Kh + gi) = kp;                     // 16B coalesced
      if (has_qh) {
        float4 q0 = *(const float4*)(qw + wi_);
        float4 q1 = *(const float4*)(qw + wi_ + 4);
        intx4 qp;
        qp[0] = pack2(a0.x * q0.x * KSCALE, a0.y * q0.y * KSCALE);
        qp[1] = pack2(a0.z * q0.z * KSCALE, a0.w * q0.w * KSCALE);
        qp[2] = pack2(a1.x * q1.x * KSCALE, a1.y * q1.y * KSCALE);
        qp[3] = pack2(a1.z * q1.z * KSCALE, a1.w * q1.w * KSCALE);
        *(intx4*)(Qh + gi) = qp;                   // 16B coalesced
      }
      unsigned short* vr = vt + r * 66 + c8;
      *(unsigned int*)(vr + 0) = (unsigned int)pack2(a0.x * v0.x, a0.y * v0.y);
      *(unsigned int*)(vr + 2) = (unsigned int)pack2(a0.z * v0.z, a0.w * v0.w);
      *(unsigned int*)(vr + 4) = (unsigned int)pack2(a1.x * v1.x, a1.y * v1.y);
      *(unsigned int*)(vr + 6) = (unsigned int)pack2(a1.z * v1.z, a1.w * v1.w);
      __syncthreads();
      // scatter this 64x64 V subtile to Vfrag (8 chunks, 1 per 64-lane group)
      {
        const int g   = tid >> 6;      // 0..7
        const int dtl = g >> 1;        // local d-tile 0..3
        const int kc  = g & 1;         // j-half 0..1
        intx4 o;
        #pragma unroll
        for (int j = 0; j < 4; ++j) {
          int row = kc * 32 + quad * 8 + 2 * j;
          int col = dtl * 16 + ln16;
          o[j] = (int)((unsigned int)vt[row * 66 + col] |
                       ((unsigned int)vt[(row + 1) * 66 + col] << 16));
        }
        size_t off = (((size_t)b * NJB + t2) * 64 +
                      (size_t)(dt2 * 4 + dtl) * 2 + kc) * 512 + (size_t)lane * 8;
        *(intx4*)(Vfrag + off) = o;
      }
      // next iteration writes the other vt buffer; the barrier above (next
      // iter) separates this scatter-read from the next write of this buffer
    }
  }

  // ================= grid-wide sync (cooperative) =================
  __threadfence();                     // publish prep writes device-wide
  cg::this_grid().sync();

  // ================= FLASH phase (round-9 v6 verbatim) =================
  const int it_ = t2 & 15;             // i-tile
  const int dh  = t2 >> 4;             // D-half 0..1
  const int i0  = it_ * BI;

  halfx8 qf[16];
  if (has_qh) {
    const unsigned short* qp =
        Qh + ((size_t)b * L_ + (i0 + w * 16 + ln16)) * D_;
    #pragma unroll
    for (int ks = 0; ks < 16; ++ks)
      qf[ks] = *(const halfx8*)(qp + ks * 32 + quad * 8);
  } else {
    const int qi = i0 + w * 16 + ln16;
    const float* ip = in + ((size_t)b * L_ + qi) * D_;
    const float* wp = qw + (size_t)qi * D_;
    #pragma unroll
    for (int ks = 0; ks < 16; ++ks) {
      int d0 = ks * 32 + quad * 8;
      float4 a0 = *(const float4*)(ip + d0);
      float4 a1 = *(const float4*)(ip + d0 + 4);
      float4 w0 = *(const float4*)(wp + d0);
      float4 w1 = *(const float4*)(wp + d0 + 4);
      halfx8 q;
      q[0] = (_Float16)(a0.x * w0.x * KSCALE);
      q[1] = (_Float16)(a0.y * w0.y * KSCALE);
      q[2] = (_Float16)(a0.z * w0.z * KSCALE);
      q[3] = (_Float16)(a0.w * w0.w * KSCALE);
      q[4] = (_Float16)(a1.x * w1.x * KSCALE);
      q[5] = (_Float16)(a1.y * w1.y * KSCALE);
      q[6] = (_Float16)(a1.z * w1.z * KSCALE);
      q[7] = (_Float16)(a1.w * w1.w * KSCALE);
      qf[ks] = q;
    }
  }

  float m_r[4], l_r[4];
  #pragma unroll
  for (int r = 0; r < 4; ++r) { m_r[r] = -1e30f; l_r[r] = 0.f; }
  floatx4 O[8][2];
  #pragma unroll
  for (int rt = 0; rt < 8; ++rt) {
    O[rt][0] = (floatx4){0.f, 0.f, 0.f, 0.f};
    O[rt][1] = (floatx4){0.f, 0.f, 0.f, 0.f};
  }

  // prologue: DMA K tile 0 into buf0 (pre-swizzled source)
  {
    const unsigned short* kb = Kh + ((size_t)b * L_ + w * 8) * D_;
    #pragma unroll
    for (int k = 0; k < 8; ++k) {
      int r = w * 8 + k;
      gld_lds16(kb + (size_t)k * D_ + ((lane ^ (r & 15)) << 3), &Ksh[0][r][0]);
    }
  }
  __syncthreads();

  int buf = 0;
  for (int jb = 0; jb < NJB; ++jb) {
    // phase 1: full QK^T (16 rows x 64 j) + wave-local softmax
    floatx4 s[4];
    s[0] = (floatx4){0.f, 0.f, 0.f, 0.f};
    s[1] = (floatx4){0.f, 0.f, 0.f, 0.f};
    s[2] = (floatx4){0.f, 0.f, 0.f, 0.f};
    s[3] = (floatx4){0.f, 0.f, 0.f, 0.f};
    #pragma unroll
    for (int ks = 0; ks < 16; ++ks) {
      #pragma unroll
      for (int jt = 0; jt < 4; ++jt) {
        halfx8 bk = *(const halfx8*)(
            &Ksh[buf][jt * 16 + ln16][((ks * 4 + quad) ^ ln16) << 3]);
        s[jt] = __builtin_amdgcn_mfma_f32_16x16x32_f16(qf[ks], bk, s[jt], 0, 0, 0);
      }
    }
    #pragma unroll
    for (int r = 0; r < 4; ++r) {
      float mx = fmaxf(fmaxf(s[0][r], s[1][r]), fmaxf(s[2][r], s[3][r]));
      #pragma unroll
      for (int off = 1; off < 16; off <<= 1) mx = fmaxf(mx, __shfl_xor(mx, off));
      float mn = fmaxf(m_r[r], mx);
      float al = exp2f(m_r[r] - mn);   // 1.0 when no update, 0 on first tile
      m_r[r] = mn;
      int row = w * 16 + quad * 4 + r;
      float ls = 0.f;
      #pragma unroll
      for (int jt = 0; jt < 4; ++jt) {
        float p = exp2f(s[jt][r] - mn);
        Psh[row][jt * 16 + ln16] = f2h_bits(p);
        ls += p;
      }
      #pragma unroll
      for (int off = 1; off < 16; off <<= 1) ls += __shfl_xor(ls, off);
      l_r[r] = l_r[r] * al + ls;
      if (ln16 == 0) Alsh[row] = al;
    }
    __syncthreads();  // barA: Psh/Alsh ready; Ksh[buf] consumed

    // phase 2: PV over this wave's 32-wide d-strip
    halfx8 vf[2][2];
    {
      const unsigned short* vb =
          Vfrag + (((size_t)b * NJB + jb) * 64) * 512 + (size_t)lane * 8;
      #pragma unroll
      for (int dt = 0; dt < 2; ++dt)
        #pragma unroll
        for (int kc = 0; kc < 2; ++kc)
          vf[dt][kc] = *(const halfx8*)(
              vb + (size_t)(((dh * 16 + w * 2 + dt) * 2 + kc)) * 512);
    }
    if (jb + 1 < NJB) {
      const unsigned short* kb =
          Kh + ((size_t)b * L_ + (jb + 1) * BJ + w * 8) * D_;
      #pragma unroll
      for (int k = 0; k < 8; ++k) {
        int r = w * 8 + k;
        gld_lds16(kb + (size_t)k * D_ + ((lane ^ (r & 15)) << 3),
                  &Ksh[buf ^ 1][r][0]);
      }
    }
    #pragma unroll
    for (int rt = 0; rt < 8; ++rt) {
      float4 alv = *(const float4*)(&Alsh[rt * 16 + quad * 4]);
      #pragma unroll
      for (int dt = 0; dt < 2; ++dt) {
        O[rt][dt][0] *= alv.x; O[rt][dt][1] *= alv.y;
        O[rt][dt][2] *= alv.z; O[rt][dt][3] *= alv.w;
      }
    }
    #pragma unroll
    for (int rt = 0; rt < 8; ++rt) {
      #pragma unroll
      for (int kc = 0; kc < 2; ++kc) {
        halfx8 pf = *(const halfx8*)(&Psh[rt * 16 + ln16][kc * 32 + quad * 8]);
        O[rt][0] = __builtin_amdgcn_mfma_f32_16x16x32_f16(pf, vf[0][kc], O[rt][0], 0, 0, 0);
        O[rt][1] = __builtin_amdgcn_mfma_f32_16x16x32_f16(pf, vf[1][kc], O[rt][1], 0, 0, 0);
      }
    }
    __syncthreads();  // barB: vmcnt(0) drain -> next K landed; Psh/Alsh free
    buf ^= 1;
  }

  // epilogue: publish l, divide, store this block's D-half
  if (ln16 == 0) {
    #pragma unroll
    for (int r = 0; r < 4; ++r) Lsh[w * 16 + quad * 4 + r] = l_r[r];
  }
  __syncthreads();
  #pragma unroll
  for (int rt = 0; rt < 8; ++rt) {
    float4 lv = *(const float4*)(&Lsh[rt * 16 + quad * 4]);
    float i0v = 1.0f / lv.x, i1v = 1.0f / lv.y;
    float i2v = 1.0f / lv.z, i3v = 1.0f / lv.w;
    float* op = out + ((size_t)b * L_ + i0 + rt * 16 + quad * 4) * D_ +
                dh * 256 + w * 32 + ln16;
    #pragma unroll
    for (int dt = 0; dt < 2; ++dt) {
      op[(size_t)0 * D_ + dt * 16] = O[rt][dt][0] * i0v;
      op[(size_t)1 * D_ + dt * 16] = O[rt][dt][1] * i1v;
      op[(size_t)2 * D_ + dt * 16] = O[rt][dt][2] * i2v;
      op[(size_t)3 * D_ + dt * 16] = O[rt][dt][3] * i3v;
    }
  }
}

// ---------------------------------------------------------------------------
extern "C" void kernel_launch(void* const* d_in, const int* in_sizes, int n_in,
                              void* d_out, int out_size, void* d_ws, size_t ws_size,
                              hipStream_t stream) {
  const float* in = (const float*)d_in[0];
  const float* qw = (const float*)d_in[1];
  const float* kw = (const float*)d_in[2];
  const float* vw = (const float*)d_in[3];
  float* out = (float*)d_out;

  const size_t seg = (size_t)B_ * L_ * D_;          // elements per f16 tensor
  unsigned short* Kh = (unsigned short*)d_ws;       // 16.78 MB (linear f16)
  unsigned short* Vf = Kh + seg;                    // 16.78 MB (fragment order)
  unsigned short* Qh = Vf + seg;                    // 16.78 MB (optional)
  int has_qh = (ws_size >= 3 * seg * sizeof(unsigned short)) ? 1 : 0;

  void* args[] = {(void*)&in, (void*)&qw, (void*)&kw, (void*)&vw,
                  (void*)&Kh, (void*)&Vf, (void*)&Qh, (void*)&out,
                  (void*)&has_qh};
  hipLaunchCooperativeKernel((void*)fused, dim3(256), dim3(512), args, 0,
                             stream);
}

// Round 13
// 246.765 us; speedup vs baseline: 1.4571x; 1.4571x over previous
//
#include <hip/hip_runtime.h>

#define B_ 8
#define L_ 2048
#define D_ 512
#define BI 128            // i-rows per block
#define BJ 64
#define NJB (L_ / BJ)     // 32

typedef __attribute__((ext_vector_type(4))) float  floatx4;
typedef __attribute__((ext_vector_type(8))) _Float16 halfx8;
typedef __attribute__((ext_vector_type(4))) int    intx4;

#define KSCALE 0.51012599f  // log2(e)/sqrt(8): exp2-domain softmax

static __device__ __forceinline__ unsigned short f2h_bits(float x) {
  _Float16 h = (_Float16)x;
  return __builtin_bit_cast(unsigned short, h);
}
static __device__ __forceinline__ int pack2(float a, float b) {
  return (int)((unsigned int)f2h_bits(a) | ((unsigned int)f2h_bits(b) << 16));
}

typedef __attribute__((address_space(1))) const unsigned short gus;
typedef __attribute__((address_space(3))) unsigned short lus;
static __device__ __forceinline__ void gld_lds16(const unsigned short* g,
                                                 unsigned short* l) {
  __builtin_amdgcn_global_load_lds((gus*)g, (lus*)l, 16, 0, 0);
}

// ---------------------------------------------------------------------------
// prep v4 = best of v1/v2 (r12 lesson: fusion loses prep parallelism AND L2
// locality; two-kernel stands):
//  * v1 shell: grid (L/64, D/64) = 256 blocks, in-block batch loop, weights
//    loaded ONCE into registers (v2's grid.z re-read weights 8x; overhead
//    79-80 us vs v1's 64-67 in recent samples).
//  * v2 stores: 16B intx4 Kh/Qh writes (2 iters of 8-elem chunks).
//  * vtile double-buffer -> 1 barrier per batch (was 2; 16 -> 8 barriers).
//    Race audit: scatter of buf p (iter b) precedes iter b+1's barrier for
//    every thread; writes to buf p resume at iter b+2, after that barrier.
// Layouts byte-identical to rounds 4-10 (proven):
//  Kh[b][l][d]=in*kw f16; Qh=in*qw*KSCALE f16 (if ws fits);
//  Vfrag[b][jb][d16*2+kc][lane][e] = MFMA-B fragment order.
// ---------------------------------------------------------------------------
__global__ __launch_bounds__(256) void prep_kvq(const float* __restrict__ in,
                                                const float* __restrict__ qw,
                                                const float* __restrict__ kw,
                                                const float* __restrict__ vw,
                                                unsigned short* __restrict__ Kh,
                                                unsigned short* __restrict__ Vfrag,
                                                unsigned short* __restrict__ Qh,
                                                int has_qh) {
  const int lt = blockIdx.x * 64;   // j-tile (== jb*64)
  const int dt = blockIdx.y * 64;   // d-tile
  const int t  = threadIdx.x;
  __shared__ unsigned short vtile[2][64][66];  // dbuf, +2 pad

  // ---- load weights once (12 float4 = 48 regs) ----
  float4 qv[2][2], kv[2][2], vv[2][2];
  #pragma unroll
  for (int i = 0; i < 2; ++i) {
    int c  = i * 256 + t;
    int r  = c >> 3;
    int c8 = (c & 7) * 8;
    size_t wi_ = (size_t)(lt + r) * D_ + (dt + c8);
    qv[i][0] = *(const float4*)(qw + wi_);
    qv[i][1] = *(const float4*)(qw + wi_ + 4);
    kv[i][0] = *(const float4*)(kw + wi_);
    kv[i][1] = *(const float4*)(kw + wi_ + 4);
    vv[i][0] = *(const float4*)(vw + wi_);
    vv[i][1] = *(const float4*)(vw + wi_ + 4);
  }
  const int wv  = t >> 6;    // wave 0..3
  const int ln  = t & 63;
  const int q4  = ln >> 4;   // quad
  const int l16 = ln & 15;

  for (int b = 0; b < B_; ++b) {
    unsigned short (*vt)[66] = vtile[b & 1];
    #pragma unroll
    for (int i = 0; i < 2; ++i) {
      int c  = i * 256 + t;
      int r  = c >> 3;
      int c8 = (c & 7) * 8;
      size_t gi = ((size_t)b * L_ + (lt + r)) * D_ + (dt + c8);
      float4 a0 = *(const float4*)(in + gi);
      float4 a1 = *(const float4*)(in + gi + 4);
      intx4 kp;
      kp[0] = pack2(a0.x * kv[i][0].x, a0.y * kv[i][0].y);
      kp[1] = pack2(a0.z * kv[i][0].z, a0.w * kv[i][0].w);
      kp[2] = pack2(a1.x * kv[i][1].x, a1.y * kv[i][1].y);
      kp[3] = pack2(a1.z * kv[i][1].z, a1.w * kv[i][1].w);
      *(intx4*)(Kh + gi) = kp;                     // 16B coalesced
      if (has_qh) {
        intx4 qp;
        qp[0] = pack2(a0.x * qv[i][0].x * KSCALE, a0.y * qv[i][0].y * KSCALE);
        qp[1] = pack2(a0.z * qv[i][0].z * KSCALE, a0.w * qv[i][0].w * KSCALE);
        qp[2] = pack2(a1.x * qv[i][1].x * KSCALE, a1.y * qv[i][1].y * KSCALE);
        qp[3] = pack2(a1.z * qv[i][1].z * KSCALE, a1.w * qv[i][1].w * KSCALE);
        *(intx4*)(Qh + gi) = qp;                   // 16B coalesced
      }
      unsigned short* vr = &vt[r][c8];
      *(unsigned int*)(vr + 0) = (unsigned int)pack2(a0.x * vv[i][0].x, a0.y * vv[i][0].y);
      *(unsigned int*)(vr + 2) = (unsigned int)pack2(a0.z * vv[i][0].z, a0.w * vv[i][0].w);
      *(unsigned int*)(vr + 4) = (unsigned int)pack2(a1.x * vv[i][1].x, a1.y * vv[i][1].y);
      *(unsigned int*)(vr + 6) = (unsigned int)pack2(a1.z * vv[i][1].z, a1.w * vv[i][1].w);
    }
    __syncthreads();  // vt ready (also fences prev batch's scatter of vt)
    // ---- scatter V in MFMA fragment order: 8 1-KB chunks, 2 per wave ----
    #pragma unroll
    for (int i = 0; i < 2; ++i) {
      int ch  = wv * 2 + i;        // 0..7
      int dtl = ch >> 1;           // local d-tile 0..3
      int kc  = ch & 1;            // j-half 0..1
      intx4 o;
      #pragma unroll
      for (int j = 0; j < 4; ++j) {
        int row = kc * 32 + q4 * 8 + 2 * j;
        int col = dtl * 16 + l16;
        o[j] = (int)((unsigned int)vt[row][col] |
                     ((unsigned int)vt[row + 1][col] << 16));
      }
      size_t off = (((size_t)b * NJB + (lt >> 6)) * 64 +
                    ((size_t)(dt >> 4) + dtl) * 2 + kc) * 512 + (size_t)ln * 8;
      *(intx4*)(Vfrag + off) = o;
    }
    // no second barrier: next batch writes the OTHER vtile buffer
  }
}

// ---------------------------------------------------------------------------
// flash v6 — VERBATIM the round-5/9 verified kernel (170.1 us, MfmaUtil 26%).
// Structural plateau, established across rounds 6-12:
//  - LDS port is the bound: ~8.4k of 12.8k cyc/jb = 8 waves x 64KB K-frag
//    ds_read_b128 + P round-trip; MFMA 26%, HBM 4%.
//  - rows/wave (the only K-traffic knob) is capped: 32 rows needs 128 Q-regs
//    -> breaches 256-VGPR arch cap (r6 spilled).
//  - j/k-splits, merged-phase, setprio, L2-direct K, fusion: all measured
//    worse or flat (r1-r4, r7, r8, r10, r12).
//  grid 256 = b(&7, XCD-pin) x i-tile(16, BI=128) x dh(2, 256-wide D-half).
//  8 waves x 512 thr, __launch_bounds__(512,2); LDS 150 KB -> 1 block/CU.
//  RULE-20: all qf/s/O/vf loops fully unrolled.
// ---------------------------------------------------------------------------
__global__ __launch_bounds__(512, 2) void flash8(const float* __restrict__ in,
                                                 const float* __restrict__ qw,
                                                 const unsigned short* __restrict__ Kh,
                                                 const unsigned short* __restrict__ Vfrag,
                                                 const unsigned short* __restrict__ Qh,
                                                 float* __restrict__ out,
                                                 int has_qh) {
  const int bid  = blockIdx.x;
  const int b    = bid & 7;            // batch == XCD (round-robin dispatch)
  const int t2   = bid >> 3;
  const int it_  = t2 & 15;            // i-tile
  const int dh   = t2 >> 4;            // D-half 0..1
  const int i0   = it_ * BI;
  const int tid  = threadIdx.x;
  const int w    = tid >> 6;
  const int lane = tid & 63;
  const int ln16 = lane & 15;
  const int quad = lane >> 4;

  __shared__ unsigned short Ksh[2][BJ][D_];  // 128 KB double-buffered
  __shared__ unsigned short Psh[BI][72];     // 18.4 KB
  __shared__ float Alsh[BI];                 // per-jb rescale alpha
  __shared__ float Lsh[BI];                  // final l

  // ---- Q fragments: rows i0 + w*16 + ln16, full K, A-layout ----
  halfx8 qf[16];
  if (has_qh) {
    const unsigned short* qp =
        Qh + ((size_t)b * L_ + (i0 + w * 16 + ln16)) * D_;
    #pragma unroll
    for (int ks = 0; ks < 16; ++ks)
      qf[ks] = *(const halfx8*)(qp + ks * 32 + quad * 8);
  } else {
    const int qi = i0 + w * 16 + ln16;
    const float* ip = in + ((size_t)b * L_ + qi) * D_;
    const float* wp = qw + (size_t)qi * D_;
    #pragma unroll
    for (int ks = 0; ks < 16; ++ks) {
      int d0 = ks * 32 + quad * 8;
      float4 a0 = *(const float4*)(ip + d0);
      float4 a1 = *(const float4*)(ip + d0 + 4);
      float4 w0 = *(const float4*)(wp + d0);
      float4 w1 = *(const float4*)(wp + d0 + 4);
      halfx8 q;
      q[0] = (_Float16)(a0.x * w0.x * KSCALE);
      q[1] = (_Float16)(a0.y * w0.y * KSCALE);
      q[2] = (_Float16)(a0.z * w0.z * KSCALE);
      q[3] = (_Float16)(a0.w * w0.w * KSCALE);
      q[4] = (_Float16)(a1.x * w1.x * KSCALE);
      q[5] = (_Float16)(a1.y * w1.y * KSCALE);
      q[6] = (_Float16)(a1.z * w1.z * KSCALE);
      q[7] = (_Float16)(a1.w * w1.w * KSCALE);
      qf[ks] = q;
    }
  }

  // softmax state for this wave's 16 rows (row = w*16 + quad*4 + r)
  float m_r[4], l_r[4];
  #pragma unroll
  for (int r = 0; r < 4; ++r) { m_r[r] = -1e30f; l_r[r] = 0.f; }
  // O accumulator: all 128 rows x this wave's 32-wide d-strip
  floatx4 O[8][2];
  #pragma unroll
  for (int rt = 0; rt < 8; ++rt) {
    O[rt][0] = (floatx4){0.f, 0.f, 0.f, 0.f};
    O[rt][1] = (floatx4){0.f, 0.f, 0.f, 0.f};
  }

  // ---- prologue: DMA K tile 0 into buf0 (pre-swizzled source) ----
  {
    const unsigned short* kb = Kh + ((size_t)b * L_ + w * 8) * D_;
    #pragma unroll
    for (int k = 0; k < 8; ++k) {
      int r = w * 8 + k;
      gld_lds16(kb + (size_t)k * D_ + ((lane ^ (r & 15)) << 3), &Ksh[0][r][0]);
    }
  }
  __syncthreads();

  int buf = 0;
  for (int jb = 0; jb < NJB; ++jb) {
    // ======== phase 1: full QK^T (16 rows x 64 j) + wave-local softmax ====
    floatx4 s[4];
    s[0] = (floatx4){0.f, 0.f, 0.f, 0.f};
    s[1] = (floatx4){0.f, 0.f, 0.f, 0.f};
    s[2] = (floatx4){0.f, 0.f, 0.f, 0.f};
    s[3] = (floatx4){0.f, 0.f, 0.f, 0.f};
    #pragma unroll
    for (int ks = 0; ks < 16; ++ks) {
      #pragma unroll
      for (int jt = 0; jt < 4; ++jt) {
        halfx8 bk = *(const halfx8*)(
            &Ksh[buf][jt * 16 + ln16][((ks * 4 + quad) ^ ln16) << 3]);
        s[jt] = __builtin_amdgcn_mfma_f32_16x16x32_f16(qf[ks], bk, s[jt], 0, 0, 0);
      }
    }
    #pragma unroll
    for (int r = 0; r < 4; ++r) {
      float mx = fmaxf(fmaxf(s[0][r], s[1][r]), fmaxf(s[2][r], s[3][r]));
      #pragma unroll
      for (int off = 1; off < 16; off <<= 1) mx = fmaxf(mx, __shfl_xor(mx, off));
      float mn = fmaxf(m_r[r], mx);
      float al = exp2f(m_r[r] - mn);   // 1.0 when no update, 0 on first tile
      m_r[r] = mn;
      int row = w * 16 + quad * 4 + r;
      float ls = 0.f;
      #pragma unroll
      for (int jt = 0; jt < 4; ++jt) {
        float p = exp2f(s[jt][r] - mn);
        Psh[row][jt * 16 + ln16] = f2h_bits(p);
        ls += p;
      }
      #pragma unroll
      for (int off = 1; off < 16; off <<= 1) ls += __shfl_xor(ls, off);
      l_r[r] = l_r[r] * al + ls;
      if (ln16 == 0) Alsh[row] = al;
    }
    __syncthreads();  // barA: Psh/Alsh ready; Ksh[buf] consumed

    // ======== phase 2: PV over this wave's 32-wide d-strip ========
    halfx8 vf[2][2];
    {
      const unsigned short* vb =
          Vfrag + (((size_t)b * NJB + jb) * 64) * 512 + (size_t)lane * 8;
      #pragma unroll
      for (int dt = 0; dt < 2; ++dt)
        #pragma unroll
        for (int kc = 0; kc < 2; ++kc)
          vf[dt][kc] = *(const halfx8*)(
              vb + (size_t)(((dh * 16 + w * 2 + dt) * 2 + kc)) * 512);
    }
    if (jb + 1 < NJB) {
      const unsigned short* kb =
          Kh + ((size_t)b * L_ + (jb + 1) * BJ + w * 8) * D_;
      #pragma unroll
      for (int k = 0; k < 8; ++k) {
        int r = w * 8 + k;
        gld_lds16(kb + (size_t)k * D_ + ((lane ^ (r & 15)) << 3),
                  &Ksh[buf ^ 1][r][0]);
      }
    }
    // rescale O by per-row alpha (broadcast reads, conflict-free)
    #pragma unroll
    for (int rt = 0; rt < 8; ++rt) {
      float4 alv = *(const float4*)(&Alsh[rt * 16 + quad * 4]);
      #pragma unroll
      for (int dt = 0; dt < 2; ++dt) {
        O[rt][dt][0] *= alv.x; O[rt][dt][1] *= alv.y;
        O[rt][dt][2] *= alv.z; O[rt][dt][3] *= alv.w;
      }
    }
    // O += P V
    #pragma unroll
    for (int rt = 0; rt < 8; ++rt) {
      #pragma unroll
      for (int kc = 0; kc < 2; ++kc) {
        halfx8 pf = *(const halfx8*)(&Psh[rt * 16 + ln16][kc * 32 + quad * 8]);
        O[rt][0] = __builtin_amdgcn_mfma_f32_16x16x32_f16(pf, vf[0][kc], O[rt][0], 0, 0, 0);
        O[rt][1] = __builtin_amdgcn_mfma_f32_16x16x32_f16(pf, vf[1][kc], O[rt][1], 0, 0, 0);
      }
    }
    __syncthreads();  // barB: vmcnt(0) drain -> next K landed; Psh/Alsh free
    buf ^= 1;
  }

  // ---- epilogue: publish l, divide, store this block's D-half ----
  if (ln16 == 0) {
    #pragma unroll
    for (int r = 0; r < 4; ++r) Lsh[w * 16 + quad * 4 + r] = l_r[r];
  }
  __syncthreads();
  #pragma unroll
  for (int rt = 0; rt < 8; ++rt) {
    float4 lv = *(const float4*)(&Lsh[rt * 16 + quad * 4]);
    float i0v = 1.0f / lv.x, i1v = 1.0f / lv.y;
    float i2v = 1.0f / lv.z, i3v = 1.0f / lv.w;
    float* op = out + ((size_t)b * L_ + i0 + rt * 16 + quad * 4) * D_ +
                dh * 256 + w * 32 + ln16;
    #pragma unroll
    for (int dt = 0; dt < 2; ++dt) {
      op[(size_t)0 * D_ + dt * 16] = O[rt][dt][0] * i0v;
      op[(size_t)1 * D_ + dt * 16] = O[rt][dt][1] * i1v;
      op[(size_t)2 * D_ + dt * 16] = O[rt][dt][2] * i2v;
      op[(size_t)3 * D_ + dt * 16] = O[rt][dt][3] * i3v;
    }
  }
}

// ---------------------------------------------------------------------------
extern "C" void kernel_launch(void* const* d_in, const int* in_sizes, int n_in,
                              void* d_out, int out_size, void* d_ws, size_t ws_size,
                              hipStream_t stream) {
  const float* in = (const float*)d_in[0];
  const float* qw = (const float*)d_in[1];
  const float* kw = (const float*)d_in[2];
  const float* vw = (const float*)d_in[3];
  float* out = (float*)d_out;

  const size_t seg = (size_t)B_ * L_ * D_;          // elements per f16 tensor
  unsigned short* Kh = (unsigned short*)d_ws;       // 16.78 MB (linear f16)
  unsigned short* Vf = Kh + seg;                    // 16.78 MB (fragment order)
  unsigned short* Qh = Vf + seg;                    // 16.78 MB (optional)
  const int has_qh = (ws_size >= 3 * seg * sizeof(unsigned short)) ? 1 : 0;

  dim3 gp(L_ / 64, D_ / 64);
  prep_kvq<<<gp, dim3(256), 0, stream>>>(in, qw, kw, vw, Kh, Vf, Qh, has_qh);
  flash8<<<dim3(256), dim3(512), 0, stream>>>(in, qw, Kh, Vf, Qh, out, has_qh);
}